// Round 9
// baseline (388.851 us; speedup 1.0000x reference)
//
#include <hip/hip_runtime.h>
#include <hip/hip_bf16.h>
#include <math.h>

#define NB 4096
#define DC 256
#define PC 512

typedef unsigned short ushort_t;
typedef __attribute__((ext_vector_type(4))) unsigned short us4;
typedef __attribute__((ext_vector_type(8))) unsigned short us8;
typedef __attribute__((ext_vector_type(8))) short s8v;       // bf16x8 for MFMA
typedef __attribute__((ext_vector_type(4))) float f32x4;

__device__ __forceinline__ float bf16_to_f(ushort_t u) {
    union { unsigned int i; float f; } c;
    c.i = ((unsigned int)u) << 16;
    return c.f;
}
__device__ __forceinline__ ushort_t f2bf(float f) {          // RNE
    union { float f; unsigned int u; } c; c.f = f;
    unsigned int r = c.u + 0x7fffu + ((c.u >> 16) & 1u);
    return (ushort_t)(r >> 16);
}

// ---------------- K0: p2 ----------------
__global__ __launch_bounds__(256) void k_prep(const float* __restrict__ proto,
                                              float* __restrict__ p2) {
    int p = blockIdx.x;
    int d = threadIdx.x;
    float v = proto[p * DC + d];
    __shared__ float red[256];
    red[d] = v * v;
    __syncthreads();
    for (int s = 128; s > 0; s >>= 1) {
        if (d < s) red[d] += red[d + s];
        __syncthreads();
    }
    if (d == 0) p2[p] = red[0];
}

// ---------------- K0a: pack proto into MFMA fragment layout, bf16 hi/lo ----------------
__global__ __launch_bounds__(256) void k_pack(const float* __restrict__ proto,
                                              ushort_t* __restrict__ pfragHi,
                                              ushort_t* __restrict__ pfragLo) {
    int idx = blockIdx.x * 256 + threadIdx.x;   // 512 blocks -> 131072
    int j  = idx & 7;
    int l  = (idx >> 3) & 63;
    int k0 = (idx >> 9) & 7;
    int nt = idx >> 12;
    int n = nt * 16 + (l & 15);
    int k = k0 * 32 + (l >> 4) * 8 + j;
    float v = proto[n * DC + k];
    ushort_t hi = f2bf(v);
    pfragHi[idx] = hi;
    pfragLo[idx] = f2bf(v - bf16_to_f(hi));
}

// ---------------- K0c: pack w3 -> B-fragments hi/lo [16 nt][5 k0][64][8], zero k>=144 ----
__global__ __launch_bounds__(256) void k_w3p(const float* __restrict__ w3,
                                             ushort_t* __restrict__ w3fH,
                                             ushort_t* __restrict__ w3fL) {
    int idx = blockIdx.x * 256 + threadIdx.x;    // 160 blocks -> 40960
    int j = idx & 7, l = (idx >> 3) & 63;
    int q = idx >> 9;
    int k0 = q % 5, nt = q / 5;
    int d = nt * 16 + (l & 15);
    int k = k0 * 32 + (l >> 4) * 8 + j;
    float v = (k < 144) ? w3[d * 144 + k] : 0.f;
    ushort_t hi = f2bf(v);
    w3fH[idx] = hi;
    w3fL[idx] = f2bf(v - bf16_to_f(hi));
}

// ---------------- K0g: pack w2 -> B-fragments hi/lo [3 k0][64][8], zero k>=72 ----------
__global__ __launch_bounds__(256) void k_w2p(const float* __restrict__ w2,
                                             ushort_t* __restrict__ w2fH,
                                             ushort_t* __restrict__ w2fL) {
    int idx = blockIdx.x * 256 + threadIdx.x;    // 6 blocks -> 1536
    int j = idx & 7, l = (idx >> 3) & 63;
    int k0 = idx >> 9;                           // 0..2
    int ch = l & 15;
    int k = k0 * 32 + (l >> 4) * 8 + j;          // 0..95
    float v = (k < 72) ? w2[ch * 72 + k] : 0.f;
    ushort_t hi = f2bf(v);
    w2fH[idx] = hi;
    w2fL[idx] = f2bf(v - bf16_to_f(hi));
}

// ---------------- K0d: pack wd1 -> bf16 B-fragments [9 nt][8 k0][64][8] ----------------
__global__ __launch_bounds__(256) void k_wd1p(const float* __restrict__ wd1,
                                              ushort_t* __restrict__ wd1frag) {
    int idx = blockIdx.x * 256 + threadIdx.x;   // 144 blocks -> 36864
    int j  = idx & 7;
    int l  = (idx >> 3) & 63;
    int k0 = (idx >> 9) & 7;
    int nt = idx >> 12;                          // 0..8
    int n = nt * 16 + (l & 15);
    int k = k0 * 32 + (l >> 4) * 8 + j;
    wd1frag[idx] = f2bf(wd1[k * 144 + n]);
}

// ---------------- K0e: wup -> B-fragments hi/lo [400 nt][8 k0][64][8]; n' = pos*256+ch ----
__global__ __launch_bounds__(256) void k_wupf(const float* __restrict__ wup,
                                              ushort_t* __restrict__ wupfH,
                                              ushort_t* __restrict__ wupfL) {
    int idx = blockIdx.x * 256 + threadIdx.x;    // 6400 blocks -> 1,638,400
    int j  = idx & 7;
    int l  = (idx >> 3) & 63;
    int k0 = (idx >> 9) & 7;
    int nt = idx >> 12;                          // 0..399
    int np = nt * 16 + (l & 15);                 // n' 0..6399
    int d  = k0 * 32 + (l >> 4) * 8 + j;         // 0..255
    int pos = np >> 8, ch = np & 255;
    float v = wup[d * 6400 + ch * 25 + pos];
    ushort_t hi = f2bf(v);
    wupfH[idx] = hi;
    wupfL[idx] = f2bf(v - bf16_to_f(hi));
}

// ---------------- K0f: PW = proto x wupT via MFMA (hi/lo), -> PWfrag [400][16][64][8] -----
__global__ __launch_bounds__(256) void k_pw2(
    const ushort_t* __restrict__ pfragHi, const ushort_t* __restrict__ pfragLo,
    const ushort_t* __restrict__ wupfH, const ushort_t* __restrict__ wupfL,
    ushort_t* __restrict__ PWfrag)
{
    int t = threadIdx.x;
    int w = t >> 6, l = t & 63, lr = l & 15, lg = l >> 4;
    int my = blockIdx.y;                 // p-tile 0..31
    int ntb = blockIdx.x * 16 + w * 4;   // n'-tile base (grid.x = 25)
    const s8v* AH = (const s8v*)pfragHi;
    const s8v* AL = (const s8v*)pfragLo;
    const s8v* BH = (const s8v*)wupfH;
    const s8v* BL = (const s8v*)wupfL;
    f32x4 acc[4];
#pragma unroll
    for (int q = 0; q < 4; q++) acc[q] = (f32x4){0.f, 0.f, 0.f, 0.f};
#pragma unroll
    for (int k0 = 0; k0 < 8; k0++) {
        s8v ah = AH[(my * 8 + k0) * 64 + l];
        s8v al = AL[(my * 8 + k0) * 64 + l];
#pragma unroll
        for (int q = 0; q < 4; q++) {
            s8v bh = BH[(size_t)((ntb + q) * 8 + k0) * 64 + l];
            s8v bl = BL[(size_t)((ntb + q) * 8 + k0) * 64 + l];
            acc[q] = __builtin_amdgcn_mfma_f32_16x16x32_bf16(ah, bh, acc[q], 0, 0, 0);
            acc[q] = __builtin_amdgcn_mfma_f32_16x16x32_bf16(al, bh, acc[q], 0, 0, 0);
            acc[q] = __builtin_amdgcn_mfma_f32_16x16x32_bf16(ah, bl, acc[q], 0, 0, 0);
        }
    }
#pragma unroll
    for (int q = 0; q < 4; q++) {
        int nt = ntb + q;
#pragma unroll
        for (int r = 0; r < 4; r++) {
            int p = my * 16 + lg * 4 + r;
            int k0p = p >> 5;
            int ll = ((p >> 3) & 3) * 16 + lr;
            int jj = p & 7;
            PWfrag[(((size_t)(nt * 16 + k0p) * 64) + ll) * 8 + jj] = f2bf(acc[q][r]);
        }
    }
}

// ---------------- E1: conv1 + conv2(MFMA) + conv3(MFMA) -> h3gP(u32 hi|lo) + x2g ----------
__global__ __launch_bounds__(512) void k_enc1(
    const float* __restrict__ x,
    const float* __restrict__ w1, const float* __restrict__ b1,
    const ushort_t* __restrict__ w2fH, const ushort_t* __restrict__ w2fL,
    const float* __restrict__ b2,
    const float* __restrict__ g2, const float* __restrict__ bt2,
    const ushort_t* __restrict__ w3fH, const ushort_t* __restrict__ w3fL,
    const float* __restrict__ b3,
    unsigned int* __restrict__ h3gP,   // [4096][25][256] u32 (hi | lo<<16)
    float* __restrict__ x2g)           // [4096][32]
{
    int b = blockIdx.x;
    int t = threadIdx.x;
    int w = t >> 6, l = t & 63, lr = l & 15, lg = l >> 4;

    __shared__ __align__(16) unsigned char buf[39168];
    __shared__ float x2s[32];
    float* xb = (float*)buf;
    float* h1 = (float*)(buf + 3136);
    ushort_t* im2Hi = (ushort_t*)(buf + 9408);
    ushort_t* im2Lo = (ushort_t*)(buf + 22720);
    float* h2 = (float*)(buf + 36032);
    ushort_t* imHi = (ushort_t*)buf;
    ushort_t* imLo = (ushort_t*)(buf + 9248);

    const float bnr = rsqrtf(1.0f + 1e-5f);

    const float* xg = x + (size_t)b * 784;
    for (int i = t; i < 784; i += 512) xb[i] = xg[i];
    if (t < 32) x2s[t] = (t < 25) ? 0.f : 1e30f;
    __syncthreads();

    // conv1 (scalar)
    for (int o = t; o < 8 * 196; o += 512) {
        int c = o / 196, r = o % 196, y = r / 14, xx = r % 14;
        float acc = b1[c];
        for (int sy = 0; sy < 3; sy++) {
            int iy = 2 * y - 1 + sy;
            if ((unsigned)iy >= 28u) continue;
            for (int sx = 0; sx < 3; sx++) {
                int ix = 2 * xx - 1 + sx;
                if ((unsigned)ix >= 28u) continue;
                acc += w1[c * 9 + sy * 3 + sx] * xb[iy * 28 + ix];
            }
        }
        h1[o] = fmaxf(acc, 0.f);
    }
    __syncthreads();

    // im2col for conv2
    for (int e = t; e < 64 * 104; e += 512) {
        int pos = e / 104, k = e % 104;
        float v = 0.f;
        if (pos < 49 && k < 72) {
            int ci = k / 9, s = k % 9;
            int sy = s / 3, sx = s % 3;
            int y = pos / 7, xx = pos % 7;
            int iy = 2 * y - 1 + sy, ix = 2 * xx - 1 + sx;
            if ((unsigned)iy < 14u && (unsigned)ix < 14u)
                v = h1[ci * 196 + iy * 14 + ix];
        }
        ushort_t hi = f2bf(v);
        im2Hi[e] = hi;
        im2Lo[e] = f2bf(v - bf16_to_f(hi));
    }
    __syncthreads();

    // conv2 as MFMA
    if (w < 4) {
        f32x4 cc = {0, 0, 0, 0};
        const s8v* WH = (const s8v*)w2fH;
        const s8v* WL = (const s8v*)w2fL;
#pragma unroll
        for (int k0 = 0; k0 < 3; k0++) {
            s8v a0 = *(const s8v*)&im2Hi[(w * 16 + lr) * 104 + k0 * 32 + lg * 8];
            s8v a1 = *(const s8v*)&im2Lo[(w * 16 + lr) * 104 + k0 * 32 + lg * 8];
            s8v bh = WH[k0 * 64 + l];
            s8v bl = WL[k0 * 64 + l];
            cc = __builtin_amdgcn_mfma_f32_16x16x32_bf16(a0, bh, cc, 0, 0, 0);
            cc = __builtin_amdgcn_mfma_f32_16x16x32_bf16(a1, bh, cc, 0, 0, 0);
            cc = __builtin_amdgcn_mfma_f32_16x16x32_bf16(a0, bl, cc, 0, 0, 0);
        }
        int ch = lr;
        float s = g2[ch] * bnr, bb = b2[ch], bt = bt2[ch];
#pragma unroll
        for (int r = 0; r < 4; r++) {
            int pos = w * 16 + lg * 4 + r;
            if (pos < 49)
                h2[ch * 49 + pos] = fmaxf((cc[r] + bb) * s + bt, 0.f);
        }
    }
    __syncthreads();

    // im2col for conv3
    for (int e = t; e < 3600; e += 512) {
        int pos = e / 144, k = e % 144;
        int ci = k / 9, s = k % 9;
        int sy = s / 3, sx = s % 3;
        int py = pos / 5, px = pos % 5;
        float v = h2[ci * 49 + (py + sy) * 7 + (px + sx)];
        ushort_t hi = f2bf(v);
        imHi[pos * 144 + k] = hi;
        imLo[pos * 144 + k] = f2bf(v - bf16_to_f(hi));
    }
    for (int e = t; e < 1024; e += 512) {
        imHi[25 * 144 + e] = 0;
        imLo[25 * 144 + e] = 0;
    }
    __syncthreads();

    // conv3 as MFMA, bias+relu; packed u32 store + x2
    {
        int nt0 = 2 * w;
        f32x4 c00 = {0,0,0,0}, c01 = {0,0,0,0}, c10 = {0,0,0,0}, c11 = {0,0,0,0};
        const s8v* WH = (const s8v*)w3fH;
        const s8v* WL = (const s8v*)w3fL;
#pragma unroll
        for (int k0 = 0; k0 < 5; k0++) {
            s8v ah0 = *(const s8v*)&imHi[lr * 144 + k0 * 32 + lg * 8];
            s8v ah1 = *(const s8v*)&imHi[(16 + lr) * 144 + k0 * 32 + lg * 8];
            s8v al0 = *(const s8v*)&imLo[lr * 144 + k0 * 32 + lg * 8];
            s8v al1 = *(const s8v*)&imLo[(16 + lr) * 144 + k0 * 32 + lg * 8];
            s8v bh0 = WH[(nt0 * 5 + k0) * 64 + l];
            s8v bl0 = WL[(nt0 * 5 + k0) * 64 + l];
            s8v bh1 = WH[((nt0 + 1) * 5 + k0) * 64 + l];
            s8v bl1 = WL[((nt0 + 1) * 5 + k0) * 64 + l];
            c00 = __builtin_amdgcn_mfma_f32_16x16x32_bf16(ah0, bh0, c00, 0, 0, 0);
            c10 = __builtin_amdgcn_mfma_f32_16x16x32_bf16(ah1, bh0, c10, 0, 0, 0);
            c00 = __builtin_amdgcn_mfma_f32_16x16x32_bf16(al0, bh0, c00, 0, 0, 0);
            c10 = __builtin_amdgcn_mfma_f32_16x16x32_bf16(al1, bh0, c10, 0, 0, 0);
            c00 = __builtin_amdgcn_mfma_f32_16x16x32_bf16(ah0, bl0, c00, 0, 0, 0);
            c10 = __builtin_amdgcn_mfma_f32_16x16x32_bf16(ah1, bl0, c10, 0, 0, 0);
            c01 = __builtin_amdgcn_mfma_f32_16x16x32_bf16(ah0, bh1, c01, 0, 0, 0);
            c11 = __builtin_amdgcn_mfma_f32_16x16x32_bf16(ah1, bh1, c11, 0, 0, 0);
            c01 = __builtin_amdgcn_mfma_f32_16x16x32_bf16(al0, bh1, c01, 0, 0, 0);
            c11 = __builtin_amdgcn_mfma_f32_16x16x32_bf16(al1, bh1, c11, 0, 0, 0);
            c01 = __builtin_amdgcn_mfma_f32_16x16x32_bf16(ah0, bl1, c01, 0, 0, 0);
            c11 = __builtin_amdgcn_mfma_f32_16x16x32_bf16(ah1, bl1, c11, 0, 0, 0);
        }
        unsigned int* hg = h3gP + (size_t)b * 6400;
#pragma unroll
        for (int q = 0; q < 2; q++) {
            int d = (nt0 + q) * 16 + lr;
            float bb = b3[d];
            f32x4 cm0 = q ? c01 : c00;
            f32x4 cm1 = q ? c11 : c10;
#pragma unroll
            for (int mt = 0; mt < 2; mt++) {
                f32x4 cv = mt ? cm1 : cm0;
#pragma unroll
                for (int r = 0; r < 4; r++) {
                    int pos = mt * 16 + lg * 4 + r;
                    if (pos < 25) {
                        float h = fmaxf(cv[r] + bb, 0.f);
                        ushort_t hi = f2bf(h);
                        ushort_t lo = f2bf(h - bf16_to_f(hi));
                        hg[pos * 256 + d] = (unsigned int)hi | ((unsigned int)lo << 16);
                        float sq = h * h;
                        sq += __shfl_xor(sq, 1);
                        sq += __shfl_xor(sq, 2);
                        sq += __shfl_xor(sq, 4);
                        sq += __shfl_xor(sq, 8);
                        if (lr == 0) atomicAdd(&x2s[pos], sq);
                    }
                }
            }
        }
    }
    __syncthreads();
    if (t < 32) x2g[(size_t)b * 32 + t] = x2s[t];
}

// ---------------- E2: MFMA distances + softmax -> md_out, Wsm (2 img/block) ----------------
__global__ __launch_bounds__(1024) void k_enc2(
    const unsigned int* __restrict__ h3gP,   // [4096][25][256] u32
    const float* __restrict__ x2g,           // [4096][32]
    const ushort_t* __restrict__ pfragHi, const ushort_t* __restrict__ pfragLo,
    const float* __restrict__ p2,
    float* __restrict__ md_out,
    ushort_t* __restrict__ Wsm)
{
    int t = threadIdx.x;
    int b0 = blockIdx.x * 2;
    int w = t >> 6, l = t & 63, lr = l & 15, lg = l >> 4;

    __shared__ __align__(16) ushort_t h3s[2][2][32][264];   // 67584 B
    __shared__ float mds[2][512];
    __shared__ float x2sh[2][32];
    __shared__ float wred[2][16];

    for (int i = t; i < 4096; i += 1024) {
        int im = i >> 11, pos = (i >> 6) & 31, c4 = i & 63;
        us4 hi = {0, 0, 0, 0}, lo = {0, 0, 0, 0};
        if (pos < 25) {
            uint4 v = *(const uint4*)&h3gP[(size_t)(b0 + im) * 6400 + pos * 256 + c4 * 4];
            hi = (us4){(ushort_t)v.x, (ushort_t)v.y, (ushort_t)v.z, (ushort_t)v.w};
            lo = (us4){(ushort_t)(v.x >> 16), (ushort_t)(v.y >> 16),
                       (ushort_t)(v.z >> 16), (ushort_t)(v.w >> 16)};
        }
        *(us4*)&h3s[im][0][pos][c4 * 4] = hi;
        *(us4*)&h3s[im][1][pos][c4 * 4] = lo;
    }
    if (t < 64) x2sh[t >> 5][t & 31] = x2g[(size_t)(b0 + (t >> 5)) * 32 + (t & 31)];
    __syncthreads();

    {
        const ushort_t* h3hi0 = &h3s[0][0][0][0];
        const ushort_t* h3lo0 = &h3s[0][1][0][0];
        const ushort_t* h3hi1 = &h3s[1][0][0][0];
        const ushort_t* h3lo1 = &h3s[1][1][0][0];
        f32x4 acc[2][2][2];
#pragma unroll
        for (int i = 0; i < 2; i++)
#pragma unroll
            for (int jm = 0; jm < 2; jm++)
#pragma unroll
                for (int mt = 0; mt < 2; mt++) acc[i][jm][mt] = (f32x4){0.f, 0.f, 0.f, 0.f};
        const s8v* BH = (const s8v*)pfragHi;
        const s8v* BL = (const s8v*)pfragLo;
        for (int k0 = 0; k0 < 8; k0++) {
            s8v ah[2][2], al[2][2];
            ah[0][0] = *(const s8v*)&h3hi0[lr * 264 + k0 * 32 + lg * 8];
            ah[0][1] = *(const s8v*)&h3hi0[(16 + lr) * 264 + k0 * 32 + lg * 8];
            al[0][0] = *(const s8v*)&h3lo0[lr * 264 + k0 * 32 + lg * 8];
            al[0][1] = *(const s8v*)&h3lo0[(16 + lr) * 264 + k0 * 32 + lg * 8];
            ah[1][0] = *(const s8v*)&h3hi1[lr * 264 + k0 * 32 + lg * 8];
            ah[1][1] = *(const s8v*)&h3hi1[(16 + lr) * 264 + k0 * 32 + lg * 8];
            al[1][0] = *(const s8v*)&h3lo1[lr * 264 + k0 * 32 + lg * 8];
            al[1][1] = *(const s8v*)&h3lo1[(16 + lr) * 264 + k0 * 32 + lg * 8];
#pragma unroll
            for (int ntq = 0; ntq < 2; ntq++) {
                int nt = w * 2 + ntq;
                s8v bh = BH[(nt * 8 + k0) * 64 + l];
                s8v bl = BL[(nt * 8 + k0) * 64 + l];
#pragma unroll
                for (int im = 0; im < 2; im++) {
                    acc[ntq][im][0] = __builtin_amdgcn_mfma_f32_16x16x32_bf16(ah[im][0], bh, acc[ntq][im][0], 0, 0, 0);
                    acc[ntq][im][1] = __builtin_amdgcn_mfma_f32_16x16x32_bf16(ah[im][1], bh, acc[ntq][im][1], 0, 0, 0);
                    acc[ntq][im][0] = __builtin_amdgcn_mfma_f32_16x16x32_bf16(al[im][0], bh, acc[ntq][im][0], 0, 0, 0);
                    acc[ntq][im][1] = __builtin_amdgcn_mfma_f32_16x16x32_bf16(al[im][1], bh, acc[ntq][im][1], 0, 0, 0);
                    acc[ntq][im][0] = __builtin_amdgcn_mfma_f32_16x16x32_bf16(ah[im][0], bl, acc[ntq][im][0], 0, 0, 0);
                    acc[ntq][im][1] = __builtin_amdgcn_mfma_f32_16x16x32_bf16(ah[im][1], bl, acc[ntq][im][1], 0, 0, 0);
                }
            }
        }
        float x2r[2][8];
#pragma unroll
        for (int im = 0; im < 2; im++)
#pragma unroll
            for (int r = 0; r < 4; r++) {
                x2r[im][r]     = x2sh[im][lg * 4 + r];
                x2r[im][4 + r] = x2sh[im][16 + lg * 4 + r];
            }
#pragma unroll
        for (int ntq = 0; ntq < 2; ntq++) {
            int pcol = (w * 2 + ntq) * 16 + lr;
            float p2v = p2[pcol];
#pragma unroll
            for (int im = 0; im < 2; im++) {
                float mm = 1e30f;
#pragma unroll
                for (int r = 0; r < 4; r++) {
                    float d0 = fmaxf(x2r[im][r]     - 2.f * acc[ntq][im][0][r] + p2v, 0.f);
                    float d1 = fmaxf(x2r[im][4 + r] - 2.f * acc[ntq][im][1][r] + p2v, 0.f);
                    mm = fminf(mm, fminf(d0, d1));
                }
                mm = fminf(mm, __shfl_xor(mm, 16));
                mm = fminf(mm, __shfl_xor(mm, 32));
                if (lg == 0) mds[im][pcol] = mm;
            }
        }
    }
    __syncthreads();

    int img = t >> 9, tt = t & 511;
    float mind = mds[img][tt];
    md_out[(size_t)(b0 + img) * PC + tt] = mind;
    float a = -mind;
    float mx = a;
#pragma unroll
    for (int off = 1; off < 64; off <<= 1) mx = fmaxf(mx, __shfl_xor(mx, off));
    int wv = w & 7;
    if (l == 0) wred[img][wv] = mx;
    __syncthreads();
    float m = wred[img][0];
#pragma unroll
    for (int i = 1; i < 8; i++) m = fmaxf(m, wred[img][i]);
    float e = expf(a - m);
    float sm = e;
#pragma unroll
    for (int off = 1; off < 64; off <<= 1) sm += __shfl_xor(sm, off);
    if (l == 0) wred[img][8 + wv] = sm;
    __syncthreads();
    float ssum = wred[img][8];
#pragma unroll
    for (int i = 9; i < 16; i++) ssum += wred[img][i];
    Wsm[(size_t)(b0 + img) * PC + tt] = f2bf(e / ssum);
}

// ---------------- K2: zupT = Wsm x PW (bf16 MFMA, 2-slab staging), bias+bn+relu ----------
__global__ __launch_bounds__(512) void k_zup2(
    const ushort_t* __restrict__ Wsm,      // [4096][512]
    const ushort_t* __restrict__ PWfrag,   // [400][16][64][8]
    const float* __restrict__ bup, const float* __restrict__ gup,
    const float* __restrict__ btup,
    ushort_t* __restrict__ zupT)           // [4096][6400]
{
    __shared__ __align__(16) ushort_t Bsh[2][8192];   // 2 buf x 2 slabs x 4096
    int t = threadIdx.x;
    int w = t >> 6, l = t & 63;
    int n0 = blockIdx.x * 128;             // 50
    int m0 = blockIdx.y * 128;             // 32
    int row = m0 + w * 16 + (l & 15);
    int krow = (l >> 4) * 8;
    f32x4 acc[8];
#pragma unroll
    for (int i = 0; i < 8; i++) acc[i] = (f32x4){0.f, 0.f, 0.f, 0.f};
    const s8v* B = (const s8v*)PWfrag;
    int base = blockIdx.x * 8 * 16;

    // stage round r covers k0 = 2r, 2r+1 (thread t loads slab0 unit t, slab1 unit t)
    {
        s8v v0 = B[(size_t)(base + (t >> 6) * 16 + 0) * 64 + (t & 63)];
        s8v v1 = B[(size_t)(base + (t >> 6) * 16 + 1) * 64 + (t & 63)];
        *(s8v*)&Bsh[0][t * 8] = v0;
        *(s8v*)&Bsh[0][4096 + t * 8] = v1;
    }
    __syncthreads();
    for (int r = 0; r < 8; r++) {
        int cur = r & 1;
        if (r < 7) {
            s8v v0 = B[(size_t)(base + (t >> 6) * 16 + 2 * r + 2) * 64 + (t & 63)];
            s8v v1 = B[(size_t)(base + (t >> 6) * 16 + 2 * r + 3) * 64 + (t & 63)];
            *(s8v*)&Bsh[cur ^ 1][t * 8] = v0;
            *(s8v*)&Bsh[cur ^ 1][4096 + t * 8] = v1;
        }
#pragma unroll
        for (int kk = 0; kk < 2; kk++) {
            int k0 = 2 * r + kk;
            s8v a = *(const s8v*)&Wsm[(size_t)row * 512 + k0 * 32 + krow];
#pragma unroll
            for (int nt = 0; nt < 8; nt++) {
                s8v bb = *(const s8v*)&Bsh[cur][kk * 4096 + (nt * 64 + l) * 8];
                acc[nt] = __builtin_amdgcn_mfma_f32_16x16x32_bf16(a, bb, acc[nt], 0, 0, 0);
            }
        }
        __syncthreads();
    }

    const float bnr = rsqrtf(1.0f + 1e-5f);
    int rowbase = m0 + w * 16 + (l >> 4) * 4;
#pragma unroll
    for (int nt = 0; nt < 8; nt++) {
        int n = n0 + nt * 16 + (l & 15);
        int ch = n & 255;
        float sc = gup[ch] * bnr, bb = bup[ch], bt = btup[ch];
#pragma unroll
        for (int r = 0; r < 4; r++) {
            float v = (acc[nt][r] + bb) * sc + bt;
            zupT[(size_t)(rowbase + r) * 6400 + n] = f2bf(fmaxf(v, 0.f));
        }
    }
}

// ---------------- K3: fused decoder, 2 images/block, conflict-free LDS ----------------
__global__ __launch_bounds__(512) void k_dtail(
    const ushort_t* __restrict__ zupT,     // [4096][6400]
    const ushort_t* __restrict__ wd1frag,  // [9][8][64][8]
    const float* __restrict__ bd1, const float* __restrict__ gd1, const float* __restrict__ btd1,
    const float* __restrict__ wd2, const float* __restrict__ bd2,
    const float* __restrict__ gd2, const float* __restrict__ btd2,
    const float* __restrict__ wd3, const float* __restrict__ bd3,
    float* __restrict__ out0)
{
    int b0 = blockIdx.x * 2, t = threadIdx.x;
    int w = t >> 6, l = t & 63, lr = l & 15, lg = l >> 4;
    int g = w >> 2, wv = w & 3, tg = t & 255;      // image group, wave-in-group
    // dbuf overlays in time: zA[2][32][264]us (33792B) -> Ps[2][25][148]f (29600B)
    //                        -> hd2T[2][8][200]f (12800B)
    __shared__ __align__(16) unsigned char dbuf[33792];
    __shared__ float hd1sT[2][16][52];     // [img][ci][pos]
    __shared__ float w2sT[9 * 8 * 16];     // [s][co][ci]
    __shared__ float w3sT[9 * 8];          // [s][ci]
    ushort_t* zAb = (ushort_t*)dbuf;       // img g at ushort offset g*8448
    float* Psb = (float*)dbuf;             // img g at float offset g*3700
    float* hd2b = (float*)dbuf;            // img g at float offset g*1600

    const float bnr = rsqrtf(1.0f + 1e-5f);

    for (int c = t; c < 1600; c += 512) {
        int im = c / 800, cc = c % 800;
        *(us8*)&zAb[im * 8448 + (cc >> 5) * 264 + (cc & 31) * 8] =
            *(const us8*)&zupT[(size_t)(b0 + im) * 6400 + cc * 8];
    }
    for (int i = t; i < 1152; i += 512) {
        int s = i >> 7, rest = i & 127;
        int co = rest >> 4, ci = rest & 15;
        w2sT[i] = wd2[(ci * 8 + co) * 9 + s];
    }
    if (t < 72) {
        int s = t >> 3, ci = t & 7;
        w3sT[t] = wd3[ci * 9 + s];
    }
    __syncthreads();

    // wd1 GEMM per image: Ps[25][144] = zA x wd1frag. 4 waves/img; wv -> nt {wv, wv+4, wv+8}
    {
        f32x4 acc[3][2];
#pragma unroll
        for (int i = 0; i < 3; i++)
#pragma unroll
            for (int mt = 0; mt < 2; mt++) acc[i][mt] = (f32x4){0.f, 0.f, 0.f, 0.f};
        const s8v* B = (const s8v*)wd1frag;
        for (int k0 = 0; k0 < 8; k0++) {
            s8v a0 = *(const s8v*)&zAb[g * 8448 + lr * 264 + k0 * 32 + lg * 8];
            s8v a1 = *(const s8v*)&zAb[g * 8448 + (16 + lr) * 264 + k0 * 32 + lg * 8];
#pragma unroll
            for (int i = 0; i < 3; i++) {
                int nt = wv + 4 * i;
                if (nt < 9) {
                    s8v bb = B[(nt * 8 + k0) * 64 + l];
                    acc[i][0] = __builtin_amdgcn_mfma_f32_16x16x32_bf16(a0, bb, acc[i][0], 0, 0, 0);
                    acc[i][1] = __builtin_amdgcn_mfma_f32_16x16x32_bf16(a1, bb, acc[i][1], 0, 0, 0);
                }
            }
        }
        __syncthreads();   // all zA reads done; Ps overlays zA
#pragma unroll
        for (int i = 0; i < 3; i++) {
            int nt = wv + 4 * i;
            if (nt < 9) {
                int col = nt * 16 + lr;
#pragma unroll
                for (int mt = 0; mt < 2; mt++)
#pragma unroll
                    for (int r = 0; r < 4; r++) {
                        int pos = mt * 16 + lg * 4 + r;
                        if (pos < 25) Psb[g * 3700 + pos * 148 + col] = acc[i][mt][r];
                    }
            }
        }
    }
    __syncthreads();

    // gather + bias + bn + relu -> hd1sT[g][ci][pos]
    for (int o = tg; o < 784; o += 256) {
        int co = o / 49, rr = o % 49, y = rr / 7, xx = rr % 7;
        float a = bd1[co];
        int sy0 = y - 4 > 0 ? y - 4 : 0, sy1 = y < 2 ? y : 2;
        for (int sy = sy0; sy <= sy1; sy++) {
            int iy = y - sy;
            int sx0 = xx - 4 > 0 ? xx - 4 : 0, sx1 = xx < 2 ? xx : 2;
            for (int sx = sx0; sx <= sx1; sx++) {
                int ix = xx - sx;
                a += Psb[g * 3700 + (iy * 5 + ix) * 148 + co * 9 + sy * 3 + sx];
            }
        }
        float v = a * (gd1[co] * bnr) + btd1[co];
        hd1sT[g][co][rr] = fmaxf(v, 0.f);
    }
    __syncthreads();   // Ps reads done; hd2b may overlay

    // wd2: convT 16->8, parity-specialized taps, scalar conflict-free reads
#define W2TAP(SY, IY, SX, IX)                                              \
    {                                                                      \
        const float* hp = &hd1sT[g][0][(IY) * 7 + (IX)];                   \
        const float* wp = &w2sT[((SY) * 3 + (SX)) * 128 + co * 16];        \
        _Pragma("unroll")                                                  \
        for (int ci = 0; ci < 16; ci++) a = fmaf(hp[ci * 52], wp[ci], a);  \
    }
    for (int o = tg; o < 8 * 196; o += 256) {
        int co = o / 196, r = o % 196, y = r / 14, xx = r % 14;
        float a = 0.f;
        if (y & 1) {
            int iyA = (y - 1) >> 1, iyB = (y + 1) >> 1;
            if (xx & 1) {
                int ixA = (xx - 1) >> 1, ixB = (xx + 1) >> 1;
                W2TAP(2, iyA, 2, ixA);
                if (xx < 13) W2TAP(2, iyA, 0, ixB);
                if (y < 13) {
                    W2TAP(0, iyB, 2, ixA);
                    if (xx < 13) W2TAP(0, iyB, 0, ixB);
                }
            } else {
                int ixA = xx >> 1;
                W2TAP(2, iyA, 1, ixA);
                if (y < 13) W2TAP(0, iyB, 1, ixA);
            }
        } else {
            int iyA = y >> 1;
            if (xx & 1) {
                int ixA = (xx - 1) >> 1, ixB = (xx + 1) >> 1;
                W2TAP(1, iyA, 2, ixA);
                if (xx < 13) W2TAP(1, iyA, 0, ixB);
            } else {
                W2TAP(1, iyA, 1, xx >> 1);
            }
        }
        float v = (a + bd2[co]) * (gd2[co] * bnr) + btd2[co];
        hd2b[g * 1600 + co * 200 + r] = fmaxf(v, 0.f);
    }
#undef W2TAP
    __syncthreads();

    // wd3 + sigmoid, parity-specialized
#define W3TAP(SY, IY, SX, IX)                                              \
    {                                                                      \
        const float* hp = &hd2b[g * 1600 + (IY) * 14 + (IX)];              \
        const float* wp = &w3sT[((SY) * 3 + (SX)) * 8];                    \
        _Pragma("unroll")                                                  \
        for (int ci = 0; ci < 8; ci++) a = fmaf(hp[ci * 200], wp[ci], a);  \
    }
    float* og = out0 + (size_t)(b0 + g) * 784;
    for (int o = tg; o < 784; o += 256) {
        int y = o / 28, xx = o % 28;
        float a = bd3[0];
        if (y & 1) {
            int iyA = (y - 1) >> 1, iyB = (y + 1) >> 1;
            if (xx & 1) {
                int ixA = (xx - 1) >> 1, ixB = (xx + 1) >> 1;
                W3TAP(2, iyA, 2, ixA);
                if (xx < 27) W3TAP(2, iyA, 0, ixB);
                if (y < 27) {
                    W3TAP(0, iyB, 2, ixA);
                    if (xx < 27) W3TAP(0, iyB, 0, ixB);
                }
            } else {
                int ixA = xx >> 1;
                W3TAP(2, iyA, 1, ixA);
                if (y < 27) W3TAP(0, iyB, 1, ixA);
            }
        } else {
            int iyA = y >> 1;
            if (xx & 1) {
                int ixA = (xx - 1) >> 1, ixB = (xx + 1) >> 1;
                W3TAP(1, iyA, 2, ixA);
                if (xx < 27) W3TAP(1, iyA, 0, ixB);
            } else {
                W3TAP(1, iyA, 1, xx >> 1);
            }
        }
        og[o] = 1.f / (1.f + expf(-a));
    }
#undef W3TAP
}

extern "C" void kernel_launch(void* const* d_in, const int* in_sizes, int n_in,
                              void* d_out, int out_size, void* d_ws, size_t ws_size,
                              hipStream_t stream) {
    const float* x    = (const float*)d_in[0];
    const float* w1   = (const float*)d_in[1];
    const float* b1   = (const float*)d_in[2];
    const float* w2   = (const float*)d_in[3];
    const float* b2   = (const float*)d_in[4];
    const float* g2   = (const float*)d_in[5];
    const float* bt2  = (const float*)d_in[6];
    const float* w3   = (const float*)d_in[7];
    const float* b3   = (const float*)d_in[8];
    const float* proto= (const float*)d_in[9];
    const float* wup  = (const float*)d_in[10];
    const float* bup  = (const float*)d_in[11];
    const float* gup  = (const float*)d_in[12];
    const float* btup = (const float*)d_in[13];
    const float* wd1  = (const float*)d_in[14];
    const float* bd1  = (const float*)d_in[15];
    const float* gd1  = (const float*)d_in[16];
    const float* btd1 = (const float*)d_in[17];
    const float* wd2  = (const float*)d_in[18];
    const float* bd2  = (const float*)d_in[19];
    const float* gd2  = (const float*)d_in[20];
    const float* btd2 = (const float*)d_in[21];
    const float* wd3  = (const float*)d_in[22];
    const float* bd3  = (const float*)d_in[23];

    float* out0   = (float*)d_out;                 // [4096][784]
    float* out_md = out0 + (size_t)NB * 784;       // [4096][512]

    // ws layout
    float*    p2      = (float*)d_ws;                          // 512 f
    float*    x2g     = p2 + 512;                              // 131072 f
    ushort_t* pfragHi = (ushort_t*)(x2g + 131072);             // 131072
    ushort_t* pfragLo = pfragHi + 131072;                      // 131072
    ushort_t* w3fH    = pfragLo + 131072;                      // 40960
    ushort_t* w3fL    = w3fH + 40960;                          // 40960
    ushort_t* w2fH    = w3fL + 40960;                          // 1536
    ushort_t* w2fL    = w2fH + 1536;                           // 1536
    ushort_t* wd1frag = w2fL + 1536;                           // 36864
    ushort_t* wupfH   = wd1frag + 36864;                       // 1638400
    ushort_t* wupfL   = wupfH + 1638400;                       // 1638400
    ushort_t* PWfrag  = wupfL + 1638400;                       // 3276800
    ushort_t* Wsm     = PWfrag + 3276800;                      // 2097152
    ushort_t* BIG     = Wsm + 2097152;                         // 104.8 MB region
    unsigned int* h3gP = (unsigned int*)BIG;                   // [4096][25][256] u32
    ushort_t* zupT    = BIG;                                   // [4096][6400] (aliases dead h3gP)

    hipLaunchKernelGGL(k_prep, dim3(PC), dim3(256), 0, stream, proto, p2);
    hipLaunchKernelGGL(k_pack, dim3(512), dim3(256), 0, stream, proto, pfragHi, pfragLo);
    hipLaunchKernelGGL(k_w3p, dim3(160), dim3(256), 0, stream, w3, w3fH, w3fL);
    hipLaunchKernelGGL(k_w2p, dim3(6), dim3(256), 0, stream, w2, w2fH, w2fL);
    hipLaunchKernelGGL(k_wd1p, dim3(144), dim3(256), 0, stream, wd1, wd1frag);
    hipLaunchKernelGGL(k_wupf, dim3(6400), dim3(256), 0, stream, wup, wupfH, wupfL);
    hipLaunchKernelGGL(k_pw2, dim3(25, 32), dim3(256), 0, stream,
                       pfragHi, pfragLo, wupfH, wupfL, PWfrag);
    hipLaunchKernelGGL(k_enc1, dim3(NB), dim3(512), 0, stream,
                       x, w1, b1, w2fH, w2fL, b2, g2, bt2, w3fH, w3fL, b3, h3gP, x2g);
    hipLaunchKernelGGL(k_enc2, dim3(NB / 2), dim3(1024), 0, stream,
                       h3gP, x2g, pfragHi, pfragLo, p2, out_md, Wsm);
    hipLaunchKernelGGL(k_zup2, dim3(50, 32), dim3(512), 0, stream,
                       Wsm, PWfrag, bup, gup, btup, zupT);
    hipLaunchKernelGGL(k_dtail, dim3(NB / 2), dim3(512), 0, stream,
                       zupT, wd1frag, bd1, gd1, btd1, wd2, bd2, gd2, btd2, wd3, bd3, out0);
}

// Round 10
// 333.738 us; speedup vs baseline: 1.1651x; 1.1651x over previous
//
#include <hip/hip_runtime.h>
#include <hip/hip_bf16.h>
#include <math.h>

#define NB 4096
#define DC 256
#define PC 512

typedef unsigned short ushort_t;
typedef __attribute__((ext_vector_type(4))) unsigned short us4;
typedef __attribute__((ext_vector_type(8))) unsigned short us8;
typedef __attribute__((ext_vector_type(8))) short s8v;       // bf16x8 for MFMA
typedef __attribute__((ext_vector_type(4))) float f32x4;

__device__ __forceinline__ float bf16_to_f(ushort_t u) {
    union { unsigned int i; float f; } c;
    c.i = ((unsigned int)u) << 16;
    return c.f;
}
__device__ __forceinline__ ushort_t f2bf(float f) {          // RNE
    union { float f; unsigned int u; } c; c.f = f;
    unsigned int r = c.u + 0x7fffu + ((c.u >> 16) & 1u);
    return (ushort_t)(r >> 16);
}

// ---------------- K0: p2 ----------------
__global__ __launch_bounds__(256) void k_prep(const float* __restrict__ proto,
                                              float* __restrict__ p2) {
    int p = blockIdx.x;
    int d = threadIdx.x;
    float v = proto[p * DC + d];
    __shared__ float red[256];
    red[d] = v * v;
    __syncthreads();
    for (int s = 128; s > 0; s >>= 1) {
        if (d < s) red[d] += red[d + s];
        __syncthreads();
    }
    if (d == 0) p2[p] = red[0];
}

// ---------------- K0a: pack proto into MFMA fragment layout, bf16 hi/lo ----------------
__global__ __launch_bounds__(256) void k_pack(const float* __restrict__ proto,
                                              ushort_t* __restrict__ pfragHi,
                                              ushort_t* __restrict__ pfragLo) {
    int idx = blockIdx.x * 256 + threadIdx.x;   // 512 blocks -> 131072
    int j  = idx & 7;
    int l  = (idx >> 3) & 63;
    int k0 = (idx >> 9) & 7;
    int nt = idx >> 12;
    int n = nt * 16 + (l & 15);
    int k = k0 * 32 + (l >> 4) * 8 + j;
    float v = proto[n * DC + k];
    ushort_t hi = f2bf(v);
    pfragHi[idx] = hi;
    pfragLo[idx] = f2bf(v - bf16_to_f(hi));
}

// ---------------- K0c: pack w3 -> B-fragments hi/lo [16 nt][5 k0][64][8], zero k>=144 ----
__global__ __launch_bounds__(256) void k_w3p(const float* __restrict__ w3,
                                             ushort_t* __restrict__ w3fH,
                                             ushort_t* __restrict__ w3fL) {
    int idx = blockIdx.x * 256 + threadIdx.x;    // 160 blocks -> 40960
    int j = idx & 7, l = (idx >> 3) & 63;
    int q = idx >> 9;
    int k0 = q % 5, nt = q / 5;
    int d = nt * 16 + (l & 15);
    int k = k0 * 32 + (l >> 4) * 8 + j;
    float v = (k < 144) ? w3[d * 144 + k] : 0.f;
    ushort_t hi = f2bf(v);
    w3fH[idx] = hi;
    w3fL[idx] = f2bf(v - bf16_to_f(hi));
}

// ---------------- K0g: pack w2 -> B-fragments hi/lo [3 k0][64][8], zero k>=72 ----------
__global__ __launch_bounds__(256) void k_w2p(const float* __restrict__ w2,
                                             ushort_t* __restrict__ w2fH,
                                             ushort_t* __restrict__ w2fL) {
    int idx = blockIdx.x * 256 + threadIdx.x;    // 6 blocks -> 1536
    int j = idx & 7, l = (idx >> 3) & 63;
    int k0 = idx >> 9;                           // 0..2
    int ch = l & 15;
    int k = k0 * 32 + (l >> 4) * 8 + j;          // 0..95
    float v = (k < 72) ? w2[ch * 72 + k] : 0.f;
    ushort_t hi = f2bf(v);
    w2fH[idx] = hi;
    w2fL[idx] = f2bf(v - bf16_to_f(hi));
}

// ---------------- K0d: pack wd1 -> bf16 B-fragments [9 nt][8 k0][64][8] ----------------
__global__ __launch_bounds__(256) void k_wd1p(const float* __restrict__ wd1,
                                              ushort_t* __restrict__ wd1frag) {
    int idx = blockIdx.x * 256 + threadIdx.x;   // 144 blocks -> 36864
    int j  = idx & 7;
    int l  = (idx >> 3) & 63;
    int k0 = (idx >> 9) & 7;
    int nt = idx >> 12;                          // 0..8
    int n = nt * 16 + (l & 15);
    int k = k0 * 32 + (l >> 4) * 8 + j;
    wd1frag[idx] = f2bf(wd1[k * 144 + n]);
}

// ---------------- K0e: wup -> B-fragments hi/lo [400 nt][8 k0][64][8]; n' = pos*256+ch ----
__global__ __launch_bounds__(256) void k_wupf(const float* __restrict__ wup,
                                              ushort_t* __restrict__ wupfH,
                                              ushort_t* __restrict__ wupfL) {
    int idx = blockIdx.x * 256 + threadIdx.x;    // 6400 blocks -> 1,638,400
    int j  = idx & 7;
    int l  = (idx >> 3) & 63;
    int k0 = (idx >> 9) & 7;
    int nt = idx >> 12;                          // 0..399
    int np = nt * 16 + (l & 15);                 // n' 0..6399
    int d  = k0 * 32 + (l >> 4) * 8 + j;         // 0..255
    int pos = np >> 8, ch = np & 255;
    float v = wup[d * 6400 + ch * 25 + pos];
    ushort_t hi = f2bf(v);
    wupfH[idx] = hi;
    wupfL[idx] = f2bf(v - bf16_to_f(hi));
}

// ---------------- K0f: PW = proto x wupT via MFMA (hi/lo), -> PWfrag [400][16][64][8] -----
__global__ __launch_bounds__(256) void k_pw2(
    const ushort_t* __restrict__ pfragHi, const ushort_t* __restrict__ pfragLo,
    const ushort_t* __restrict__ wupfH, const ushort_t* __restrict__ wupfL,
    ushort_t* __restrict__ PWfrag)
{
    int t = threadIdx.x;
    int w = t >> 6, l = t & 63, lr = l & 15, lg = l >> 4;
    int my = blockIdx.y;                 // p-tile 0..31
    int ntb = blockIdx.x * 16 + w * 4;   // n'-tile base (grid.x = 25)
    const s8v* AH = (const s8v*)pfragHi;
    const s8v* AL = (const s8v*)pfragLo;
    const s8v* BH = (const s8v*)wupfH;
    const s8v* BL = (const s8v*)wupfL;
    f32x4 acc[4];
#pragma unroll
    for (int q = 0; q < 4; q++) acc[q] = (f32x4){0.f, 0.f, 0.f, 0.f};
#pragma unroll
    for (int k0 = 0; k0 < 8; k0++) {
        s8v ah = AH[(my * 8 + k0) * 64 + l];
        s8v al = AL[(my * 8 + k0) * 64 + l];
#pragma unroll
        for (int q = 0; q < 4; q++) {
            s8v bh = BH[(size_t)((ntb + q) * 8 + k0) * 64 + l];
            s8v bl = BL[(size_t)((ntb + q) * 8 + k0) * 64 + l];
            acc[q] = __builtin_amdgcn_mfma_f32_16x16x32_bf16(ah, bh, acc[q], 0, 0, 0);
            acc[q] = __builtin_amdgcn_mfma_f32_16x16x32_bf16(al, bh, acc[q], 0, 0, 0);
            acc[q] = __builtin_amdgcn_mfma_f32_16x16x32_bf16(ah, bl, acc[q], 0, 0, 0);
        }
    }
#pragma unroll
    for (int q = 0; q < 4; q++) {
        int nt = ntb + q;
#pragma unroll
        for (int r = 0; r < 4; r++) {
            int p = my * 16 + lg * 4 + r;
            int k0p = p >> 5;
            int ll = ((p >> 3) & 3) * 16 + lr;
            int jj = p & 7;
            PWfrag[(((size_t)(nt * 16 + k0p) * 64) + ll) * 8 + jj] = f2bf(acc[q][r]);
        }
    }
}

// ---------------- E1: conv1 + conv2(MFMA) + conv3(MFMA) -> h3gP(u32 hi|lo) + x2g ----------
__global__ __launch_bounds__(512) void k_enc1(
    const float* __restrict__ x,
    const float* __restrict__ w1, const float* __restrict__ b1,
    const ushort_t* __restrict__ w2fH, const ushort_t* __restrict__ w2fL,
    const float* __restrict__ b2,
    const float* __restrict__ g2, const float* __restrict__ bt2,
    const ushort_t* __restrict__ w3fH, const ushort_t* __restrict__ w3fL,
    const float* __restrict__ b3,
    unsigned int* __restrict__ h3gP,   // [4096][25][256] u32 (hi | lo<<16)
    float* __restrict__ x2g)           // [4096][32]
{
    int b = blockIdx.x;
    int t = threadIdx.x;
    int w = t >> 6, l = t & 63, lr = l & 15, lg = l >> 4;

    __shared__ __align__(16) unsigned char buf[39168];
    __shared__ float x2s[32];
    float* xb = (float*)buf;
    float* h1 = (float*)(buf + 3136);
    ushort_t* im2Hi = (ushort_t*)(buf + 9408);
    ushort_t* im2Lo = (ushort_t*)(buf + 22720);
    float* h2 = (float*)(buf + 36032);
    ushort_t* imHi = (ushort_t*)buf;
    ushort_t* imLo = (ushort_t*)(buf + 9248);

    const float bnr = rsqrtf(1.0f + 1e-5f);

    const float* xg = x + (size_t)b * 784;
    for (int i = t; i < 784; i += 512) xb[i] = xg[i];
    if (t < 32) x2s[t] = (t < 25) ? 0.f : 1e30f;
    __syncthreads();

    // conv1 (scalar)
    for (int o = t; o < 8 * 196; o += 512) {
        int c = o / 196, r = o % 196, y = r / 14, xx = r % 14;
        float acc = b1[c];
        for (int sy = 0; sy < 3; sy++) {
            int iy = 2 * y - 1 + sy;
            if ((unsigned)iy >= 28u) continue;
            for (int sx = 0; sx < 3; sx++) {
                int ix = 2 * xx - 1 + sx;
                if ((unsigned)ix >= 28u) continue;
                acc += w1[c * 9 + sy * 3 + sx] * xb[iy * 28 + ix];
            }
        }
        h1[o] = fmaxf(acc, 0.f);
    }
    __syncthreads();

    // im2col for conv2
    for (int e = t; e < 64 * 104; e += 512) {
        int pos = e / 104, k = e % 104;
        float v = 0.f;
        if (pos < 49 && k < 72) {
            int ci = k / 9, s = k % 9;
            int sy = s / 3, sx = s % 3;
            int y = pos / 7, xx = pos % 7;
            int iy = 2 * y - 1 + sy, ix = 2 * xx - 1 + sx;
            if ((unsigned)iy < 14u && (unsigned)ix < 14u)
                v = h1[ci * 196 + iy * 14 + ix];
        }
        ushort_t hi = f2bf(v);
        im2Hi[e] = hi;
        im2Lo[e] = f2bf(v - bf16_to_f(hi));
    }
    __syncthreads();

    // conv2 as MFMA
    if (w < 4) {
        f32x4 cc = {0, 0, 0, 0};
        const s8v* WH = (const s8v*)w2fH;
        const s8v* WL = (const s8v*)w2fL;
#pragma unroll
        for (int k0 = 0; k0 < 3; k0++) {
            s8v a0 = *(const s8v*)&im2Hi[(w * 16 + lr) * 104 + k0 * 32 + lg * 8];
            s8v a1 = *(const s8v*)&im2Lo[(w * 16 + lr) * 104 + k0 * 32 + lg * 8];
            s8v bh = WH[k0 * 64 + l];
            s8v bl = WL[k0 * 64 + l];
            cc = __builtin_amdgcn_mfma_f32_16x16x32_bf16(a0, bh, cc, 0, 0, 0);
            cc = __builtin_amdgcn_mfma_f32_16x16x32_bf16(a1, bh, cc, 0, 0, 0);
            cc = __builtin_amdgcn_mfma_f32_16x16x32_bf16(a0, bl, cc, 0, 0, 0);
        }
        int ch = lr;
        float s = g2[ch] * bnr, bb = b2[ch], bt = bt2[ch];
#pragma unroll
        for (int r = 0; r < 4; r++) {
            int pos = w * 16 + lg * 4 + r;
            if (pos < 49)
                h2[ch * 49 + pos] = fmaxf((cc[r] + bb) * s + bt, 0.f);
        }
    }
    __syncthreads();

    // im2col for conv3
    for (int e = t; e < 3600; e += 512) {
        int pos = e / 144, k = e % 144;
        int ci = k / 9, s = k % 9;
        int sy = s / 3, sx = s % 3;
        int py = pos / 5, px = pos % 5;
        float v = h2[ci * 49 + (py + sy) * 7 + (px + sx)];
        ushort_t hi = f2bf(v);
        imHi[pos * 144 + k] = hi;
        imLo[pos * 144 + k] = f2bf(v - bf16_to_f(hi));
    }
    for (int e = t; e < 1024; e += 512) {
        imHi[25 * 144 + e] = 0;
        imLo[25 * 144 + e] = 0;
    }
    __syncthreads();

    // conv3 as MFMA, bias+relu; packed u32 store + x2
    {
        int nt0 = 2 * w;
        f32x4 c00 = {0,0,0,0}, c01 = {0,0,0,0}, c10 = {0,0,0,0}, c11 = {0,0,0,0};
        const s8v* WH = (const s8v*)w3fH;
        const s8v* WL = (const s8v*)w3fL;
#pragma unroll
        for (int k0 = 0; k0 < 5; k0++) {
            s8v ah0 = *(const s8v*)&imHi[lr * 144 + k0 * 32 + lg * 8];
            s8v ah1 = *(const s8v*)&imHi[(16 + lr) * 144 + k0 * 32 + lg * 8];
            s8v al0 = *(const s8v*)&imLo[lr * 144 + k0 * 32 + lg * 8];
            s8v al1 = *(const s8v*)&imLo[(16 + lr) * 144 + k0 * 32 + lg * 8];
            s8v bh0 = WH[(nt0 * 5 + k0) * 64 + l];
            s8v bl0 = WL[(nt0 * 5 + k0) * 64 + l];
            s8v bh1 = WH[((nt0 + 1) * 5 + k0) * 64 + l];
            s8v bl1 = WL[((nt0 + 1) * 5 + k0) * 64 + l];
            c00 = __builtin_amdgcn_mfma_f32_16x16x32_bf16(ah0, bh0, c00, 0, 0, 0);
            c10 = __builtin_amdgcn_mfma_f32_16x16x32_bf16(ah1, bh0, c10, 0, 0, 0);
            c00 = __builtin_amdgcn_mfma_f32_16x16x32_bf16(al0, bh0, c00, 0, 0, 0);
            c10 = __builtin_amdgcn_mfma_f32_16x16x32_bf16(al1, bh0, c10, 0, 0, 0);
            c00 = __builtin_amdgcn_mfma_f32_16x16x32_bf16(ah0, bl0, c00, 0, 0, 0);
            c10 = __builtin_amdgcn_mfma_f32_16x16x32_bf16(ah1, bl0, c10, 0, 0, 0);
            c01 = __builtin_amdgcn_mfma_f32_16x16x32_bf16(ah0, bh1, c01, 0, 0, 0);
            c11 = __builtin_amdgcn_mfma_f32_16x16x32_bf16(ah1, bh1, c11, 0, 0, 0);
            c01 = __builtin_amdgcn_mfma_f32_16x16x32_bf16(al0, bh1, c01, 0, 0, 0);
            c11 = __builtin_amdgcn_mfma_f32_16x16x32_bf16(al1, bh1, c11, 0, 0, 0);
            c01 = __builtin_amdgcn_mfma_f32_16x16x32_bf16(ah0, bl1, c01, 0, 0, 0);
            c11 = __builtin_amdgcn_mfma_f32_16x16x32_bf16(ah1, bl1, c11, 0, 0, 0);
        }
        unsigned int* hg = h3gP + (size_t)b * 6400;
#pragma unroll
        for (int q = 0; q < 2; q++) {
            int d = (nt0 + q) * 16 + lr;
            float bb = b3[d];
            f32x4 cm0 = q ? c01 : c00;
            f32x4 cm1 = q ? c11 : c10;
#pragma unroll
            for (int mt = 0; mt < 2; mt++) {
                f32x4 cv = mt ? cm1 : cm0;
#pragma unroll
                for (int r = 0; r < 4; r++) {
                    int pos = mt * 16 + lg * 4 + r;
                    if (pos < 25) {
                        float h = fmaxf(cv[r] + bb, 0.f);
                        ushort_t hi = f2bf(h);
                        ushort_t lo = f2bf(h - bf16_to_f(hi));
                        hg[pos * 256 + d] = (unsigned int)hi | ((unsigned int)lo << 16);
                        float sq = h * h;
                        sq += __shfl_xor(sq, 1);
                        sq += __shfl_xor(sq, 2);
                        sq += __shfl_xor(sq, 4);
                        sq += __shfl_xor(sq, 8);
                        if (lr == 0) atomicAdd(&x2s[pos], sq);
                    }
                }
            }
        }
    }
    __syncthreads();
    if (t < 32) x2g[(size_t)b * 32 + t] = x2s[t];
}

// ---------------- E2: MFMA distances + softmax -> md_out, Wsm (2 img/block) ----------------
__global__ __launch_bounds__(1024) void k_enc2(
    const unsigned int* __restrict__ h3gP,   // [4096][25][256] u32
    const float* __restrict__ x2g,           // [4096][32]
    const ushort_t* __restrict__ pfragHi, const ushort_t* __restrict__ pfragLo,
    const float* __restrict__ p2,
    float* __restrict__ md_out,
    ushort_t* __restrict__ Wsm)
{
    int t = threadIdx.x;
    int b0 = blockIdx.x * 2;
    int w = t >> 6, l = t & 63, lr = l & 15, lg = l >> 4;

    __shared__ __align__(16) ushort_t h3s[2][2][32][264];   // 67584 B
    __shared__ float mds[2][512];
    __shared__ float x2sh[2][32];
    __shared__ float wred[2][16];

    for (int i = t; i < 4096; i += 1024) {
        int im = i >> 11, pos = (i >> 6) & 31, c4 = i & 63;
        us4 hi = {0, 0, 0, 0}, lo = {0, 0, 0, 0};
        if (pos < 25) {
            uint4 v = *(const uint4*)&h3gP[(size_t)(b0 + im) * 6400 + pos * 256 + c4 * 4];
            hi = (us4){(ushort_t)v.x, (ushort_t)v.y, (ushort_t)v.z, (ushort_t)v.w};
            lo = (us4){(ushort_t)(v.x >> 16), (ushort_t)(v.y >> 16),
                       (ushort_t)(v.z >> 16), (ushort_t)(v.w >> 16)};
        }
        *(us4*)&h3s[im][0][pos][c4 * 4] = hi;
        *(us4*)&h3s[im][1][pos][c4 * 4] = lo;
    }
    if (t < 64) x2sh[t >> 5][t & 31] = x2g[(size_t)(b0 + (t >> 5)) * 32 + (t & 31)];
    __syncthreads();

    {
        const ushort_t* h3hi0 = &h3s[0][0][0][0];
        const ushort_t* h3lo0 = &h3s[0][1][0][0];
        const ushort_t* h3hi1 = &h3s[1][0][0][0];
        const ushort_t* h3lo1 = &h3s[1][1][0][0];
        f32x4 acc[2][2][2];
#pragma unroll
        for (int i = 0; i < 2; i++)
#pragma unroll
            for (int jm = 0; jm < 2; jm++)
#pragma unroll
                for (int mt = 0; mt < 2; mt++) acc[i][jm][mt] = (f32x4){0.f, 0.f, 0.f, 0.f};
        const s8v* BH = (const s8v*)pfragHi;
        const s8v* BL = (const s8v*)pfragLo;
        for (int k0 = 0; k0 < 8; k0++) {
            s8v ah[2][2], al[2][2];
            ah[0][0] = *(const s8v*)&h3hi0[lr * 264 + k0 * 32 + lg * 8];
            ah[0][1] = *(const s8v*)&h3hi0[(16 + lr) * 264 + k0 * 32 + lg * 8];
            al[0][0] = *(const s8v*)&h3lo0[lr * 264 + k0 * 32 + lg * 8];
            al[0][1] = *(const s8v*)&h3lo0[(16 + lr) * 264 + k0 * 32 + lg * 8];
            ah[1][0] = *(const s8v*)&h3hi1[lr * 264 + k0 * 32 + lg * 8];
            ah[1][1] = *(const s8v*)&h3hi1[(16 + lr) * 264 + k0 * 32 + lg * 8];
            al[1][0] = *(const s8v*)&h3lo1[lr * 264 + k0 * 32 + lg * 8];
            al[1][1] = *(const s8v*)&h3lo1[(16 + lr) * 264 + k0 * 32 + lg * 8];
#pragma unroll
            for (int ntq = 0; ntq < 2; ntq++) {
                int nt = w * 2 + ntq;
                s8v bh = BH[(nt * 8 + k0) * 64 + l];
                s8v bl = BL[(nt * 8 + k0) * 64 + l];
#pragma unroll
                for (int im = 0; im < 2; im++) {
                    acc[ntq][im][0] = __builtin_amdgcn_mfma_f32_16x16x32_bf16(ah[im][0], bh, acc[ntq][im][0], 0, 0, 0);
                    acc[ntq][im][1] = __builtin_amdgcn_mfma_f32_16x16x32_bf16(ah[im][1], bh, acc[ntq][im][1], 0, 0, 0);
                    acc[ntq][im][0] = __builtin_amdgcn_mfma_f32_16x16x32_bf16(al[im][0], bh, acc[ntq][im][0], 0, 0, 0);
                    acc[ntq][im][1] = __builtin_amdgcn_mfma_f32_16x16x32_bf16(al[im][1], bh, acc[ntq][im][1], 0, 0, 0);
                    acc[ntq][im][0] = __builtin_amdgcn_mfma_f32_16x16x32_bf16(ah[im][0], bl, acc[ntq][im][0], 0, 0, 0);
                    acc[ntq][im][1] = __builtin_amdgcn_mfma_f32_16x16x32_bf16(ah[im][1], bl, acc[ntq][im][1], 0, 0, 0);
                }
            }
        }
        float x2r[2][8];
#pragma unroll
        for (int im = 0; im < 2; im++)
#pragma unroll
            for (int r = 0; r < 4; r++) {
                x2r[im][r]     = x2sh[im][lg * 4 + r];
                x2r[im][4 + r] = x2sh[im][16 + lg * 4 + r];
            }
#pragma unroll
        for (int ntq = 0; ntq < 2; ntq++) {
            int pcol = (w * 2 + ntq) * 16 + lr;
            float p2v = p2[pcol];
#pragma unroll
            for (int im = 0; im < 2; im++) {
                float mm = 1e30f;
#pragma unroll
                for (int r = 0; r < 4; r++) {
                    float d0 = fmaxf(x2r[im][r]     - 2.f * acc[ntq][im][0][r] + p2v, 0.f);
                    float d1 = fmaxf(x2r[im][4 + r] - 2.f * acc[ntq][im][1][r] + p2v, 0.f);
                    mm = fminf(mm, fminf(d0, d1));
                }
                mm = fminf(mm, __shfl_xor(mm, 16));
                mm = fminf(mm, __shfl_xor(mm, 32));
                if (lg == 0) mds[im][pcol] = mm;
            }
        }
    }
    __syncthreads();

    int img = t >> 9, tt = t & 511;
    float mind = mds[img][tt];
    md_out[(size_t)(b0 + img) * PC + tt] = mind;
    float a = -mind;
    float mx = a;
#pragma unroll
    for (int off = 1; off < 64; off <<= 1) mx = fmaxf(mx, __shfl_xor(mx, off));
    int wv = w & 7;
    if (l == 0) wred[img][wv] = mx;
    __syncthreads();
    float m = wred[img][0];
#pragma unroll
    for (int i = 1; i < 8; i++) m = fmaxf(m, wred[img][i]);
    float e = expf(a - m);
    float sm = e;
#pragma unroll
    for (int off = 1; off < 64; off <<= 1) sm += __shfl_xor(sm, off);
    if (l == 0) wred[img][8 + wv] = sm;
    __syncthreads();
    float ssum = wred[img][8];
#pragma unroll
    for (int i = 9; i < 16; i++) ssum += wred[img][i];
    Wsm[(size_t)(b0 + img) * PC + tt] = f2bf(e / ssum);
}

// ---------------- K2: zupT = Wsm x PW (bf16 MFMA, 2-slab staging), bias+bn+relu ----------
__global__ __launch_bounds__(512) void k_zup2(
    const ushort_t* __restrict__ Wsm,      // [4096][512]
    const ushort_t* __restrict__ PWfrag,   // [400][16][64][8]
    const float* __restrict__ bup, const float* __restrict__ gup,
    const float* __restrict__ btup,
    ushort_t* __restrict__ zupT)           // [4096][6400]
{
    __shared__ __align__(16) ushort_t Bsh[2][8192];
    int t = threadIdx.x;
    int w = t >> 6, l = t & 63;
    int n0 = blockIdx.x * 128;             // 50
    int m0 = blockIdx.y * 128;             // 32
    int row = m0 + w * 16 + (l & 15);
    int krow = (l >> 4) * 8;
    f32x4 acc[8];
#pragma unroll
    for (int i = 0; i < 8; i++) acc[i] = (f32x4){0.f, 0.f, 0.f, 0.f};
    const s8v* B = (const s8v*)PWfrag;
    int base = blockIdx.x * 8 * 16;

    {
        s8v v0 = B[(size_t)(base + (t >> 6) * 16 + 0) * 64 + (t & 63)];
        s8v v1 = B[(size_t)(base + (t >> 6) * 16 + 1) * 64 + (t & 63)];
        *(s8v*)&Bsh[0][t * 8] = v0;
        *(s8v*)&Bsh[0][4096 + t * 8] = v1;
    }
    __syncthreads();
    for (int r = 0; r < 8; r++) {
        int cur = r & 1;
        if (r < 7) {
            s8v v0 = B[(size_t)(base + (t >> 6) * 16 + 2 * r + 2) * 64 + (t & 63)];
            s8v v1 = B[(size_t)(base + (t >> 6) * 16 + 2 * r + 3) * 64 + (t & 63)];
            *(s8v*)&Bsh[cur ^ 1][t * 8] = v0;
            *(s8v*)&Bsh[cur ^ 1][4096 + t * 8] = v1;
        }
#pragma unroll
        for (int kk = 0; kk < 2; kk++) {
            int k0 = 2 * r + kk;
            s8v a = *(const s8v*)&Wsm[(size_t)row * 512 + k0 * 32 + krow];
#pragma unroll
            for (int nt = 0; nt < 8; nt++) {
                s8v bb = *(const s8v*)&Bsh[cur][kk * 4096 + (nt * 64 + l) * 8];
                acc[nt] = __builtin_amdgcn_mfma_f32_16x16x32_bf16(a, bb, acc[nt], 0, 0, 0);
            }
        }
        __syncthreads();
    }

    const float bnr = rsqrtf(1.0f + 1e-5f);
    int rowbase = m0 + w * 16 + (l >> 4) * 4;
#pragma unroll
    for (int nt = 0; nt < 8; nt++) {
        int n = n0 + nt * 16 + (l & 15);
        int ch = n & 255;
        float sc = gup[ch] * bnr, bb = bup[ch], bt = btup[ch];
#pragma unroll
        for (int r = 0; r < 4; r++) {
            float v = (acc[nt][r] + bb) * sc + bt;
            zupT[(size_t)(rowbase + r) * 6400 + n] = f2bf(fmaxf(v, 0.f));
        }
    }
}

// ---------------- K3: fused decoder, 2 img/block, class-per-wave (uniform branches) -------
__global__ __launch_bounds__(512) void k_dtail(
    const ushort_t* __restrict__ zupT,     // [4096][6400]
    const ushort_t* __restrict__ wd1frag,  // [9][8][64][8]
    const float* __restrict__ bd1, const float* __restrict__ gd1, const float* __restrict__ btd1,
    const float* __restrict__ wd2, const float* __restrict__ bd2,
    const float* __restrict__ gd2, const float* __restrict__ btd2,
    const float* __restrict__ wd3, const float* __restrict__ bd3,
    float* __restrict__ out0)
{
    int b0 = blockIdx.x * 2, t = threadIdx.x;
    int w = t >> 6, l = t & 63, lr = l & 15, lg = l >> 4;
    int g = w >> 2, wv = w & 3, tg = t & 255;      // image, wave-in-image
    // dbuf time-multiplex: zA[2][32][264]us (33792B) -> Ps[2][25][148]f (29600B)
    //                      -> hd2p[2][8][225]f (14464B, img g at float ofs g*1808)
    __shared__ __align__(16) unsigned char dbuf[33792];
    __shared__ float hd1p[2][16][64];      // [img][ci][8x8 grid], row/col 7 = zero pad
    __shared__ float w2sT[9 * 8 * 16];     // [s][co][ci]
    __shared__ float w3sT[9 * 8];          // [s][ci]
    ushort_t* zAb = (ushort_t*)dbuf;
    float* Psb = (float*)dbuf;

    const float bnr = rsqrtf(1.0f + 1e-5f);

    // phase 1: stage zA, weights, zero hd1p
    for (int c = t; c < 1600; c += 512) {
        int im = c / 800, cc = c % 800;
        *(us8*)&zAb[im * 8448 + (cc >> 5) * 264 + (cc & 31) * 8] =
            *(const us8*)&zupT[(size_t)(b0 + im) * 6400 + cc * 8];
    }
    for (int i = t; i < 2048; i += 512) ((float*)hd1p)[i] = 0.f;
    for (int i = t; i < 1152; i += 512) {
        int s = i >> 7, rest = i & 127;
        int co = rest >> 4, ci = rest & 15;
        w2sT[i] = wd2[(ci * 8 + co) * 9 + s];
    }
    if (t < 72) {
        int s = t >> 3, ci = t & 7;
        w3sT[t] = wd3[ci * 9 + s];
    }
    __syncthreads();

    // phase 2: wd1 MFMA  Ps[25][144] = zA x wd1frag (4 waves/img; wv -> nt {wv,wv+4,wv+8})
    {
        f32x4 acc[3][2];
#pragma unroll
        for (int i = 0; i < 3; i++)
#pragma unroll
            for (int mt = 0; mt < 2; mt++) acc[i][mt] = (f32x4){0.f, 0.f, 0.f, 0.f};
        const s8v* B = (const s8v*)wd1frag;
        for (int k0 = 0; k0 < 8; k0++) {
            s8v a0 = *(const s8v*)&zAb[g * 8448 + lr * 264 + k0 * 32 + lg * 8];
            s8v a1 = *(const s8v*)&zAb[g * 8448 + (16 + lr) * 264 + k0 * 32 + lg * 8];
#pragma unroll
            for (int i = 0; i < 3; i++) {
                int nt = wv + 4 * i;
                if (nt < 9) {
                    s8v bb = B[(nt * 8 + k0) * 64 + l];
                    acc[i][0] = __builtin_amdgcn_mfma_f32_16x16x32_bf16(a0, bb, acc[i][0], 0, 0, 0);
                    acc[i][1] = __builtin_amdgcn_mfma_f32_16x16x32_bf16(a1, bb, acc[i][1], 0, 0, 0);
                }
            }
        }
        __syncthreads();   // zA dead; Ps overlays
#pragma unroll
        for (int i = 0; i < 3; i++) {
            int nt = wv + 4 * i;
            if (nt < 9) {
                int col = nt * 16 + lr;
#pragma unroll
                for (int mt = 0; mt < 2; mt++)
#pragma unroll
                    for (int r = 0; r < 4; r++) {
                        int pos = mt * 16 + lg * 4 + r;
                        if (pos < 25) Psb[g * 3700 + pos * 148 + col] = acc[i][mt][r];
                    }
            }
        }
    }
    __syncthreads();

    // phase 3: gather + bias + bn + relu -> hd1p[g][co][y*8+xx]
    for (int o = tg; o < 784; o += 256) {
        int co = o / 49, rr = o % 49, y = rr / 7, xx = rr % 7;
        float a = bd1[co];
        int sy0 = y - 4 > 0 ? y - 4 : 0, sy1 = y < 2 ? y : 2;
        for (int sy = sy0; sy <= sy1; sy++) {
            int iy = y - sy;
            int sx0 = xx - 4 > 0 ? xx - 4 : 0, sx1 = xx < 2 ? xx : 2;
            for (int sx = sx0; sx <= sx1; sx++) {
                int ix = xx - sx;
                a += Psb[g * 3700 + (iy * 5 + ix) * 148 + co * 9 + sy * 3 + sx];
            }
        }
        float v = a * (gd1[co] * bnr) + btd1[co];
        hd1p[g][co][y * 8 + xx] = fmaxf(v, 0.f);
    }
    __syncthreads();   // Ps dead; hd2p overlays dbuf

    // phase 4: wd2 (class-per-wave, branch-free borders via zero pad) + hd2p pad zeroing
    {
        // zero hd2p pad slots (row 14, col 14): disjoint from valid writes below
        if (t < 464) {
            int im = t / 232, rest = t % 232;       // 232 = 8co * 29
            int co = rest / 29, s = rest % 29;
            int yy = (s < 15) ? 14 : (s - 15);
            int xx2 = (s < 15) ? s : 14;
            ((float*)dbuf)[im * 1808 + co * 225 + yy * 15 + xx2] = 0.f;
        }
        int cls = (wv + g) & 3;                     // spread heavy class over SIMDs
        int cy = cls >> 1, cx = cls & 1;
        if (l < 56 && (l & 7) < 7) {
            int r = l >> 3, c = l & 7;              // class-grid position (0..6)^2
            float acc[8];
#pragma unroll
            for (int co = 0; co < 8; co++) acc[co] = 0.f;
            const float* hb = &hd1p[g][0][0];
            int niy = 1 + cy, nix = 1 + cx;
            for (int ty = 0; ty < niy; ty++) {
                int iy = r + ty;
                int sy = cy ? (ty ? 0 : 2) : 1;
                for (int tx = 0; tx < nix; tx++) {
                    int ix = c + tx;
                    int sx = cx ? (tx ? 0 : 2) : 1;
                    const float* wp = &w2sT[(sy * 3 + sx) * 128];
                    int hoff = iy * 8 + ix;
                    float h[16];
#pragma unroll
                    for (int ci = 0; ci < 16; ci++) h[ci] = hb[ci * 64 + hoff];
#pragma unroll
                    for (int co = 0; co < 8; co++) {
                        const float4* wp4 = (const float4*)&wp[co * 16];
                        float4 wa = wp4[0], wb4 = wp4[1], wc4 = wp4[2], wd4 = wp4[3];
                        float a = acc[co];
                        a = fmaf(h[0], wa.x, a);  a = fmaf(h[1], wa.y, a);
                        a = fmaf(h[2], wa.z, a);  a = fmaf(h[3], wa.w, a);
                        a = fmaf(h[4], wb4.x, a); a = fmaf(h[5], wb4.y, a);
                        a = fmaf(h[6], wb4.z, a); a = fmaf(h[7], wb4.w, a);
                        a = fmaf(h[8], wc4.x, a); a = fmaf(h[9], wc4.y, a);
                        a = fmaf(h[10], wc4.z, a); a = fmaf(h[11], wc4.w, a);
                        a = fmaf(h[12], wd4.x, a); a = fmaf(h[13], wd4.y, a);
                        a = fmaf(h[14], wd4.z, a); a = fmaf(h[15], wd4.w, a);
                        acc[co] = a;
                    }
                }
            }
            int y = 2 * r + cy, x = 2 * c + cx;     // output position 0..13
            float* hout = (float*)dbuf + g * 1808;
#pragma unroll
            for (int co = 0; co < 8; co++) {
                float v = (acc[co] + bd2[co]) * (gd2[co] * bnr) + btd2[co];
                hout[co * 225 + y * 15 + x] = fmaxf(v, 0.f);
            }
        }
    }
    __syncthreads();

    // phase 5: wd3 + sigmoid (class-per-wave over 14x14 class grid)
    {
        int cls = (wv + g) & 3;
        int cy = cls >> 1, cx = cls & 1;
        const float* h2b = (const float*)dbuf + g * 1808;
        float* og = out0 + (size_t)(b0 + g) * 784;
        int niy = 1 + cy, nix = 1 + cx;
#pragma unroll
        for (int j = 0; j < 4; j++) {
            int idx = l + 64 * j;                  // padded 14x16 grid
            if (idx < 224) {
                int row = idx >> 4, col = idx & 15;
                if (col < 14) {
                    float a = bd3[0];
                    for (int ty = 0; ty < niy; ty++) {
                        int iy = row + ty;
                        int sy = cy ? (ty ? 0 : 2) : 1;
                        for (int tx = 0; tx < nix; tx++) {
                            int ix = col + tx;
                            int sx = cx ? (tx ? 0 : 2) : 1;
                            const float* wp = &w3sT[(sy * 3 + sx) * 8];
                            int hoff = iy * 15 + ix;
#pragma unroll
                            for (int ci = 0; ci < 8; ci++)
                                a = fmaf(h2b[ci * 225 + hoff], wp[ci], a);
                        }
                    }
                    int y = 2 * row + cy, x = 2 * col + cx;
                    og[y * 28 + x] = 1.f / (1.f + expf(-a));
                }
            }
        }
    }
}

extern "C" void kernel_launch(void* const* d_in, const int* in_sizes, int n_in,
                              void* d_out, int out_size, void* d_ws, size_t ws_size,
                              hipStream_t stream) {
    const float* x    = (const float*)d_in[0];
    const float* w1   = (const float*)d_in[1];
    const float* b1   = (const float*)d_in[2];
    const float* w2   = (const float*)d_in[3];
    const float* b2   = (const float*)d_in[4];
    const float* g2   = (const float*)d_in[5];
    const float* bt2  = (const float*)d_in[6];
    const float* w3   = (const float*)d_in[7];
    const float* b3   = (const float*)d_in[8];
    const float* proto= (const float*)d_in[9];
    const float* wup  = (const float*)d_in[10];
    const float* bup  = (const float*)d_in[11];
    const float* gup  = (const float*)d_in[12];
    const float* btup = (const float*)d_in[13];
    const float* wd1  = (const float*)d_in[14];
    const float* bd1  = (const float*)d_in[15];
    const float* gd1  = (const float*)d_in[16];
    const float* btd1 = (const float*)d_in[17];
    const float* wd2  = (const float*)d_in[18];
    const float* bd2  = (const float*)d_in[19];
    const float* gd2  = (const float*)d_in[20];
    const float* btd2 = (const float*)d_in[21];
    const float* wd3  = (const float*)d_in[22];
    const float* bd3  = (const float*)d_in[23];

    float* out0   = (float*)d_out;                 // [4096][784]
    float* out_md = out0 + (size_t)NB * 784;       // [4096][512]

    // ws layout
    float*    p2      = (float*)d_ws;                          // 512 f
    float*    x2g     = p2 + 512;                              // 131072 f
    ushort_t* pfragHi = (ushort_t*)(x2g + 131072);             // 131072
    ushort_t* pfragLo = pfragHi + 131072;                      // 131072
    ushort_t* w3fH    = pfragLo + 131072;                      // 40960
    ushort_t* w3fL    = w3fH + 40960;                          // 40960
    ushort_t* w2fH    = w3fL + 40960;                          // 1536
    ushort_t* w2fL    = w2fH + 1536;                           // 1536
    ushort_t* wd1frag = w2fL + 1536;                           // 36864
    ushort_t* wupfH   = wd1frag + 36864;                       // 1638400
    ushort_t* wupfL   = wupfH + 1638400;                       // 1638400
    ushort_t* PWfrag  = wupfL + 1638400;                       // 3276800
    ushort_t* Wsm     = PWfrag + 3276800;                      // 2097152
    ushort_t* BIG     = Wsm + 2097152;                         // 104.8 MB region
    unsigned int* h3gP = (unsigned int*)BIG;                   // [4096][25][256] u32
    ushort_t* zupT    = BIG;                                   // [4096][6400] (aliases dead h3gP)

    hipLaunchKernelGGL(k_prep, dim3(PC), dim3(256), 0, stream, proto, p2);
    hipLaunchKernelGGL(k_pack, dim3(512), dim3(256), 0, stream, proto, pfragHi, pfragLo);
    hipLaunchKernelGGL(k_w3p, dim3(160), dim3(256), 0, stream, w3, w3fH, w3fL);
    hipLaunchKernelGGL(k_w2p, dim3(6), dim3(256), 0, stream, w2, w2fH, w2fL);
    hipLaunchKernelGGL(k_wd1p, dim3(144), dim3(256), 0, stream, wd1, wd1frag);
    hipLaunchKernelGGL(k_wupf, dim3(6400), dim3(256), 0, stream, wup, wupfH, wupfL);
    hipLaunchKernelGGL(k_pw2, dim3(25, 32), dim3(256), 0, stream,
                       pfragHi, pfragLo, wupfH, wupfL, PWfrag);
    hipLaunchKernelGGL(k_enc1, dim3(NB), dim3(512), 0, stream,
                       x, w1, b1, w2fH, w2fL, b2, g2, bt2, w3fH, w3fL, b3, h3gP, x2g);
    hipLaunchKernelGGL(k_enc2, dim3(NB / 2), dim3(1024), 0, stream,
                       h3gP, x2g, pfragHi, pfragLo, p2, out_md, Wsm);
    hipLaunchKernelGGL(k_zup2, dim3(50, 32), dim3(512), 0, stream,
                       Wsm, PWfrag, bup, gup, btup, zupT);
    hipLaunchKernelGGL(k_dtail, dim3(NB / 2), dim3(512), 0, stream,
                       zupT, wd1frag, bd1, gd1, btd1, wd2, bd2, gd2, btd2, wd3, bd3, out0);
}